// Round 18
// baseline (484.984 us; speedup 1.0000x reference)
//
#include <hip/hip_runtime.h>
#include <hip/hip_bf16.h>

#define N_NODES_C 100000
#define N_EDGES_C 1600000
#define HID 128
#define OUTD 8
#define N_GRAPHS_C 128
#define SEG 8     // pool segments per graph
#define NBUCK 256 // CSR sort buckets
#define BSZ 391   // nodes per bucket (256*391 = 100096 >= 100000)
#define BCAP 8192 // LDS capacity per bucket in k_sort2
#define CHUNK 2048
#define EPT 8     // edges per thread in k_scatter1
#define NTILES (N_NODES_C / 16)              // 6250
#define NTPW 4                               // node-tiles per wave in gemm
#define NGRP ((NTILES + NTPW - 1) / NTPW)    // 1563

typedef __attribute__((ext_vector_type(4))) float f4;
typedef __attribute__((ext_vector_type(4))) _Float16 h4;
typedef __attribute__((ext_vector_type(8))) _Float16 f16x8;
typedef __attribute__((ext_vector_type(4))) float f32x4;

static inline size_t align_up(size_t x, size_t a) { return (x + a - 1) & ~(a - 1); }

__device__ __forceinline__ f4 h2f(h4 v) { return __builtin_convertvector(v, f4); }
__device__ __forceinline__ h4 f2h(f4 v) { return __builtin_convertvector(v, h4); }

__global__ __launch_bounds__(256) void k_cvt(const float* __restrict__ in,
                                             _Float16* __restrict__ out) {
    int i = blockIdx.x * blockDim.x + threadIdx.x;
    f4 v = *(const f4*)(in + (size_t)i * 4);
    *(h4*)(out + (size_t)i * 4) = f2h(v);
}

// Build wT fp16 [L][2][j][k] from W_rel/W_root fp32 [L][k][j]
__global__ __launch_bounds__(128) void k_wprep(
    const float* __restrict__ W_rel, const float* __restrict__ W_root,
    _Float16* __restrict__ wT) {
    const int b = blockIdx.x;
    const int l = b >> 8;
    const int m = (b >> 7) & 1;
    const int j = b & 127;
    const int k = threadIdx.x;
    const float* W = (m == 0 ? W_rel : W_root) + (size_t)l * HID * HID;
    wT[(((size_t)l * 2 + m) * HID + j) * HID + k] = (_Float16)W[k * HID + j];
}

// ==================== CSR build: 2-pass LDS-staged bucket sort ====================

__global__ __launch_bounds__(256) void k_zeroB(int* __restrict__ b) { b[threadIdx.x] = 0; }

__global__ __launch_bounds__(256) void k_hist1(const int* __restrict__ dst,
                                               int* __restrict__ bhist) {
    __shared__ int h[NBUCK];
    h[threadIdx.x] = 0;
    __syncthreads();
    int stride = gridDim.x * blockDim.x;
    for (int e = blockIdx.x * 256 + threadIdx.x; e < N_EDGES_C; e += stride)
        atomicAdd(&h[dst[e] / BSZ], 1);
    __syncthreads();
    if (h[threadIdx.x]) atomicAdd(&bhist[threadIdx.x], h[threadIdx.x]);
}

__global__ __launch_bounds__(256) void k_bscan(const int* __restrict__ bhist,
                                               int* __restrict__ bbase,
                                               int* __restrict__ bcursor) {
    __shared__ int s[NBUCK];
    const int tid = threadIdx.x;
    int v = bhist[tid];
    s[tid] = v;
    __syncthreads();
    for (int off = 1; off < NBUCK; off <<= 1) {
        int t = (tid >= off) ? s[tid - off] : 0;
        __syncthreads();
        s[tid] += t;
        __syncthreads();
    }
    int excl = s[tid] - v;
    bbase[tid] = excl;
    bcursor[tid] = excl;
    if (tid == NBUCK - 1) bbase[NBUCK] = N_EDGES_C;
}

__global__ __launch_bounds__(256) void k_scatter1(
    const int* __restrict__ src, const int* __restrict__ dst,
    int* __restrict__ bcursor, unsigned* __restrict__ tmp) {
    __shared__ int h[NBUCK], sc[NBUCK], gb[NBUCK], lc[NBUCK];
    __shared__ unsigned lbuf[CHUNK];
    const int tid = threadIdx.x;
    const int base = blockIdx.x * CHUNK;
    h[tid] = 0; lc[tid] = 0;
    __syncthreads();
    unsigned rec[EPT]; int bk[EPT];
#pragma unroll
    for (int i = 0; i < EPT; ++i) {
        int e = base + i * 256 + tid;
        if (e < N_EDGES_C) {
            int d = dst[e];
            int b = d / BSZ;
            rec[i] = ((unsigned)src[e] << 9) | (unsigned)(d - b * BSZ);
            bk[i] = b;
            atomicAdd(&h[b], 1);
        } else bk[i] = -1;
    }
    __syncthreads();
    int v = h[tid];
    sc[tid] = v;
    __syncthreads();
    for (int off = 1; off < NBUCK; off <<= 1) {
        int t = (tid >= off) ? sc[tid - off] : 0;
        __syncthreads();
        sc[tid] += t;
        __syncthreads();
    }
    int excl = sc[tid] - v;
    gb[tid] = v ? atomicAdd(&bcursor[tid], v) : 0;
    sc[tid] = excl;
    __syncthreads();
#pragma unroll
    for (int i = 0; i < EPT; ++i) {
        if (bk[i] >= 0) {
            int p = atomicAdd(&lc[bk[i]], 1);
            lbuf[sc[bk[i]] + p] = rec[i];
        }
    }
    __syncthreads();
    const int wid = tid >> 6, lane = tid & 63;
    for (int b = wid; b < NBUCK; b += 4) {
        int n = h[b], g = gb[b], l = sc[b];
        for (int i = lane; i < n; i += 64) tmp[g + i] = lbuf[l + i];
    }
}

__global__ __launch_bounds__(256) void k_sort2(
    const unsigned* __restrict__ tmp, const int* __restrict__ bbase,
    int* __restrict__ offsets, int* __restrict__ es) {
    __shared__ int h[512], s2[512], cur[512];
    __shared__ int lbuf[BCAP];
    const int b = blockIdx.x, tid = threadIdx.x;
    const int base = bbase[b];
    const int cnt = bbase[b + 1] - base;
    h[tid] = 0; h[tid + 256] = 0;
    __syncthreads();
    for (int i = tid; i < cnt; i += 256) atomicAdd(&h[tmp[base + i] & 511], 1);
    __syncthreads();
    int v0 = h[tid], v1 = h[tid + 256];
    s2[tid] = v0; s2[tid + 256] = v1;
    __syncthreads();
    for (int off = 1; off < 512; off <<= 1) {
        int t0 = (tid >= off) ? s2[tid - off] : 0;
        int t1 = (tid + 256 >= off) ? s2[tid + 256 - off] : 0;
        __syncthreads();
        s2[tid] += t0; s2[tid + 256] += t1;
        __syncthreads();
    }
    int e0 = s2[tid] - v0, e1 = s2[tid + 256] - v1;
    cur[tid] = e0; cur[tid + 256] = e1;
    {
        int gn0 = b * BSZ + tid;
        if (tid < BSZ && gn0 < N_NODES_C) offsets[gn0] = base + e0;
        int n1 = tid + 256;
        int gn1 = b * BSZ + n1;
        if (n1 < BSZ && gn1 < N_NODES_C) offsets[gn1] = base + e1;
    }
    __syncthreads();
    for (int i = tid; i < cnt; i += 256) {
        unsigned r = tmp[base + i];
        int ld = r & 511;
        int p = atomicAdd(&cur[ld], 1);
        lbuf[p] = (int)(r >> 9);
    }
    __syncthreads();
    for (int i = tid; i < cnt; i += 256) es[base + i] = lbuf[i];
    if (b == NBUCK - 1 && tid == 0) offsets[N_NODES_C] = N_EDGES_C;
}

// ==================== layers ====================

// Gather-sum: one 32-lane group per node. No LDS, no barriers -> max TLP.
__global__ __launch_bounds__(256) void k_gather(
    const _Float16* __restrict__ h_in, _Float16* __restrict__ agg,
    const int* __restrict__ offsets, const int* __restrict__ es) {
    const int node = (blockIdx.x << 3) + (threadIdx.x >> 5);
    const int lane = threadIdx.x & 31;
    const int c4 = lane * 4;
    const int beg = offsets[node];
    const int end = offsets[node + 1];
    f4 a0 = {0.f, 0.f, 0.f, 0.f}, a1 = a0, a2 = a0, a3 = a0;
    f4 a4 = a0, a5 = a0, a6 = a0, a7 = a0;
    int e = beg;
    for (; e + 8 <= end; e += 8) {
        int s0 = es[e],     s1 = es[e + 1], s2 = es[e + 2], s3 = es[e + 3];
        int s4 = es[e + 4], s5 = es[e + 5], s6 = es[e + 6], s7 = es[e + 7];
        h4 v0 = *(const h4*)(h_in + (size_t)s0 * HID + c4);
        h4 v1 = *(const h4*)(h_in + (size_t)s1 * HID + c4);
        h4 v2 = *(const h4*)(h_in + (size_t)s2 * HID + c4);
        h4 v3 = *(const h4*)(h_in + (size_t)s3 * HID + c4);
        h4 v4 = *(const h4*)(h_in + (size_t)s4 * HID + c4);
        h4 v5 = *(const h4*)(h_in + (size_t)s5 * HID + c4);
        h4 v6 = *(const h4*)(h_in + (size_t)s6 * HID + c4);
        h4 v7 = *(const h4*)(h_in + (size_t)s7 * HID + c4);
        a0 += h2f(v0); a1 += h2f(v1); a2 += h2f(v2); a3 += h2f(v3);
        a4 += h2f(v4); a5 += h2f(v5); a6 += h2f(v6); a7 += h2f(v7);
    }
    for (; e + 4 <= end; e += 4) {
        int s0 = es[e], s1 = es[e + 1], s2 = es[e + 2], s3 = es[e + 3];
        h4 v0 = *(const h4*)(h_in + (size_t)s0 * HID + c4);
        h4 v1 = *(const h4*)(h_in + (size_t)s1 * HID + c4);
        h4 v2 = *(const h4*)(h_in + (size_t)s2 * HID + c4);
        h4 v3 = *(const h4*)(h_in + (size_t)s3 * HID + c4);
        a0 += h2f(v0); a1 += h2f(v1); a2 += h2f(v2); a3 += h2f(v3);
    }
    for (; e < end; ++e)
        a0 += h2f(*(const h4*)(h_in + (size_t)es[e] * HID + c4));
    f4 t = ((a0 + a1) + (a2 + a3)) + ((a4 + a5) + (a6 + a7));
    *(h4*)(agg + (size_t)node * HID + c4) = f2h(t);
}

// MFMA GEMM, software-pipelined: wave owns a 16-j tile, loops NTPW node-tiles
// with explicit register double-buffer (issue nt+1 loads before nt's MFMAs).
// r15 post-mortem: W fragments already resident (AGPR); cost was unpipelined
// A/H load latency + only 6256 waves. Now 12504 waves + prefetch.
__global__ __launch_bounds__(256, 4) void k_gemm_mfma(
    const _Float16* __restrict__ agg, const _Float16* __restrict__ h_in,
    _Float16* __restrict__ h_out,
    const _Float16* __restrict__ wT,   // [2][HID][HID] (j,k) for this layer
    const float* __restrict__ b_rel) {
    const int wave = (blockIdx.x << 2) + (threadIdx.x >> 6);  // 0..NGRP*8-1
    const int lane = threadIdx.x & 63;
    const int g = wave >> 3;       // ntile group
    const int jt = wave & 7;
    const int row = lane & 15;
    const int kg = lane >> 4;      // 0..3
    const int j0 = jt << 4;
    const int j = j0 + row;
    const float b = b_rel[j];

    const _Float16* wrP = wT + (size_t)(j0 + row) * HID + (kg << 3);
    const _Float16* woP = wT + (size_t)(HID + j0 + row) * HID + (kg << 3);
    const f16x8 bR0 = *(const f16x8*)(wrP + 0);
    const f16x8 bR1 = *(const f16x8*)(wrP + 32);
    const f16x8 bR2 = *(const f16x8*)(wrP + 64);
    const f16x8 bR3 = *(const f16x8*)(wrP + 96);
    const f16x8 bO0 = *(const f16x8*)(woP + 0);
    const f16x8 bO1 = *(const f16x8*)(woP + 32);
    const f16x8 bO2 = *(const f16x8*)(woP + 64);
    const f16x8 bO3 = *(const f16x8*)(woP + 96);

    const int ntBeg = g * NTPW;
    const int ntEnd = (ntBeg + NTPW < NTILES) ? ntBeg + NTPW : NTILES;
    const size_t rowOff = (size_t)row * HID + (kg << 3);
    const _Float16* aP = agg  + ((size_t)ntBeg << 4) * HID + rowOff;
    const _Float16* hP = h_in + ((size_t)ntBeg << 4) * HID + rowOff;

    // prologue: load fragments for first ntile
    f16x8 cA0 = *(const f16x8*)(aP + 0),  cA1 = *(const f16x8*)(aP + 32);
    f16x8 cA2 = *(const f16x8*)(aP + 64), cA3 = *(const f16x8*)(aP + 96);
    f16x8 cH0 = *(const f16x8*)(hP + 0),  cH1 = *(const f16x8*)(hP + 32);
    f16x8 cH2 = *(const f16x8*)(hP + 64), cH3 = *(const f16x8*)(hP + 96);

    for (int nt = ntBeg; nt < ntEnd; ++nt) {
        // issue next ntile's loads BEFORE this ntile's MFMA chain
        f16x8 nA0, nA1, nA2, nA3, nH0, nH1, nH2, nH3;
        if (nt + 1 < ntEnd) {
            nA0 = *(const f16x8*)(aP + 2048 + 0);  nA1 = *(const f16x8*)(aP + 2048 + 32);
            nA2 = *(const f16x8*)(aP + 2048 + 64); nA3 = *(const f16x8*)(aP + 2048 + 96);
            nH0 = *(const f16x8*)(hP + 2048 + 0);  nH1 = *(const f16x8*)(hP + 2048 + 32);
            nH2 = *(const f16x8*)(hP + 2048 + 64); nH3 = *(const f16x8*)(hP + 2048 + 96);
        }
        // two independent 4-MFMA chains (halve serial depth), sum at end
        f32x4 acc1 = {0.f, 0.f, 0.f, 0.f}, acc2 = acc1;
        acc1 = __builtin_amdgcn_mfma_f32_16x16x32_f16(cA0, bR0, acc1, 0, 0, 0);
        acc2 = __builtin_amdgcn_mfma_f32_16x16x32_f16(cA2, bR2, acc2, 0, 0, 0);
        acc1 = __builtin_amdgcn_mfma_f32_16x16x32_f16(cH0, bO0, acc1, 0, 0, 0);
        acc2 = __builtin_amdgcn_mfma_f32_16x16x32_f16(cH2, bO2, acc2, 0, 0, 0);
        acc1 = __builtin_amdgcn_mfma_f32_16x16x32_f16(cA1, bR1, acc1, 0, 0, 0);
        acc2 = __builtin_amdgcn_mfma_f32_16x16x32_f16(cA3, bR3, acc2, 0, 0, 0);
        acc1 = __builtin_amdgcn_mfma_f32_16x16x32_f16(cH1, bO1, acc1, 0, 0, 0);
        acc2 = __builtin_amdgcn_mfma_f32_16x16x32_f16(cH3, bO3, acc2, 0, 0, 0);
        const f32x4 acc = acc1 + acc2;
        const int node0 = nt << 4;
#pragma unroll
        for (int r = 0; r < 4; ++r) {
            float v = atanf(acc[r] + b);
            h_out[(size_t)(node0 + (kg << 2) + r) * HID + j] = (_Float16)v;
        }
        cA0 = nA0; cA1 = nA1; cA2 = nA2; cA3 = nA3;
        cH0 = nH0; cH1 = nH1; cH2 = nH2; cH3 = nH3;
        aP += 2048; hP += 2048;
    }
}

// Pool stage 1: per (graph, segment) partial sums over fp16 h -> fp32 part
__global__ __launch_bounds__(256) void k_pool1(
    const _Float16* __restrict__ h, const int* __restrict__ batch,
    float* __restrict__ part) {
    __shared__ float sm[2][HID];
    const int b = blockIdx.x;
    const int g = b >> 3, s = b & (SEG - 1);
    const int j = threadIdx.x & 127;
    const int half = threadIdx.x >> 7;

    int lo = 0, hi = N_NODES_C;
    while (lo < hi) { int mid = (lo + hi) >> 1; if (batch[mid] < g) lo = mid + 1; else hi = mid; }
    int start = lo;
    hi = N_NODES_C;
    while (lo < hi) { int mid = (lo + hi) >> 1; if (batch[mid] < g + 1) lo = mid + 1; else hi = mid; }
    int end = lo;
    int len = end - start;
    int s0 = start + (int)((long long)len * s / SEG);
    int s1 = start + (int)((long long)len * (s + 1) / SEG);

    float acc = 0.f;
    for (int i = s0 + half; i < s1; i += 2) acc += (float)h[(size_t)i * HID + j];
    sm[half][j] = acc;
    __syncthreads();
    if (threadIdx.x < HID) part[(size_t)b * HID + j] = sm[0][j] + sm[1][j];
}

// Pool stage 2 + head
__global__ __launch_bounds__(128) void k_head(
    const float* __restrict__ part, const float* __restrict__ W_out,
    const float* __restrict__ b_out, float* __restrict__ out) {
    __shared__ float sf[HID];
    const int g = blockIdx.x;
    const int j = threadIdx.x;
    float v = 0.f;
    for (int s = 0; s < SEG; ++s) v += part[(size_t)(g * SEG + s) * HID + j];
    sf[j] = v;
    __syncthreads();
    if (j < OUTD) {
        float a = b_out[j];
        for (int k = 0; k < HID; ++k) a += sf[k] * W_out[k * OUTD + j];
        out[g * OUTD + j] = 1.f / (1.f + expf(-a));
    }
}

extern "C" void kernel_launch(void* const* d_in, const int* in_sizes, int n_in,
                              void* d_out, int out_size, void* d_ws, size_t ws_size,
                              hipStream_t stream) {
    const float* x      = (const float*)d_in[0];
    const int*   ei     = (const int*)d_in[1];
    const int*   src    = ei;
    const int*   dst    = ei + N_EDGES_C;
    const int*   batch  = (const int*)d_in[2];
    const float* W_rel  = (const float*)d_in[3];
    const float* b_rel  = (const float*)d_in[4];
    const float* W_root = (const float*)d_in[5];
    const float* W_out  = (const float*)d_in[6];
    const float* b_out  = (const float*)d_in[7];
    float* out = (float*)d_out;

    char* ws = (char*)d_ws;
    size_t off = 0;
    auto alloc = [&](size_t bytes) { void* p = ws + off; off = align_up(off + bytes, 256); return p; };
    _Float16* xh    = (_Float16*)alloc((size_t)N_NODES_C * HID * 2);
    _Float16* h1h   = (_Float16*)alloc((size_t)N_NODES_C * HID * 2);
    _Float16* agg16 = (_Float16*)alloc((size_t)N_NODES_C * HID * 2);
    _Float16* wT    = (_Float16*)alloc((size_t)3 * 2 * HID * HID * 2);
    int*   offsets = (int*)alloc((size_t)(N_NODES_C + 1) * sizeof(int));
    int*   es      = (int*)alloc((size_t)N_EDGES_C * sizeof(int));
    unsigned* tmp  = (unsigned*)alloc((size_t)N_EDGES_C * sizeof(unsigned));
    int*   bhist   = (int*)alloc(NBUCK * sizeof(int));
    int*   bbase   = (int*)alloc((NBUCK + 1) * sizeof(int));
    int*   bcursor = (int*)alloc(NBUCK * sizeof(int));
    float* part    = (float*)alloc((size_t)N_GRAPHS_C * SEG * HID * sizeof(float));

    const int gather_blocks = N_NODES_C / 8;          // 12500
    const int mfma_blocks = NGRP * 2;                 // NGRP*8 waves / 4 = 3126
    const int scat_blocks = (N_EDGES_C + CHUNK - 1) / CHUNK;
    const size_t WTL = (size_t)2 * HID * HID;

    // ---- weight prep + x -> fp16 ----
    k_wprep<<<768, 128, 0, stream>>>(W_rel, W_root, wT);
    k_cvt<<<(N_NODES_C * HID) / 4 / 256, 256, 0, stream>>>(x, xh);

    // ---- CSR build: bucket sort, all global scatter staged through LDS ----
    k_zeroB<<<1, 256, 0, stream>>>(bhist);
    k_hist1<<<1024, 256, 0, stream>>>(dst, bhist);
    k_bscan<<<1, 256, 0, stream>>>(bhist, bbase, bcursor);
    k_scatter1<<<scat_blocks, 256, 0, stream>>>(src, dst, bcursor, tmp);
    k_sort2<<<NBUCK, 256, 0, stream>>>(tmp, bbase, offsets, es);

    // ---- 3 GraphConv layers: gather (latency-opt) + MFMA gemm (pipelined) ----
    k_gather<<<gather_blocks, 256, 0, stream>>>(xh, agg16, offsets, es);
    k_gemm_mfma<<<mfma_blocks, 256, 0, stream>>>(agg16, xh, h1h, wT + 0 * WTL, b_rel + 0 * HID);
    k_gather<<<gather_blocks, 256, 0, stream>>>(h1h, agg16, offsets, es);
    k_gemm_mfma<<<mfma_blocks, 256, 0, stream>>>(agg16, h1h, xh, wT + 1 * WTL, b_rel + 1 * HID);
    k_gather<<<gather_blocks, 256, 0, stream>>>(xh, agg16, offsets, es);
    k_gemm_mfma<<<mfma_blocks, 256, 0, stream>>>(agg16, xh, h1h, wT + 2 * WTL, b_rel + 2 * HID);

    // ---- pool + head ----
    k_pool1<<<N_GRAPHS_C * SEG, 256, 0, stream>>>(h1h, batch, part);
    k_head<<<N_GRAPHS_C, 128, 0, stream>>>(part, W_out, b_out, out);
}

// Round 19
// 475.611 us; speedup vs baseline: 1.0197x; 1.0197x over previous
//
#include <hip/hip_runtime.h>
#include <hip/hip_bf16.h>

#define N_NODES_C 100000
#define N_EDGES_C 1600000
#define HID 128
#define OUTD 8
#define N_GRAPHS_C 128
#define SEG 8     // pool segments per graph
#define NBUCK 256 // CSR sort buckets
#define BSZ 391   // nodes per bucket
#define BCAP 8192
#define CHUNK 2048
#define EPT 8
#define TPX 782   // gemm tiles per XCD (granule pairs {x+16t, x+16t+8})

typedef __attribute__((ext_vector_type(4))) float f4;
typedef __attribute__((ext_vector_type(4))) _Float16 h4;
typedef __attribute__((ext_vector_type(8))) _Float16 f16x8;
typedef __attribute__((ext_vector_type(4))) float f32x4;

static inline size_t align_up(size_t x, size_t a) { return (x + a - 1) & ~(a - 1); }

__device__ __forceinline__ f4 h2f(h4 v) { return __builtin_convertvector(v, f4); }
__device__ __forceinline__ h4 f2h(f4 v) { return __builtin_convertvector(v, h4); }

__global__ __launch_bounds__(256) void k_cvt(const float* __restrict__ in,
                                             _Float16* __restrict__ out) {
    int i = blockIdx.x * blockDim.x + threadIdx.x;
    f4 v = *(const f4*)(in + (size_t)i * 4);
    *(h4*)(out + (size_t)i * 4) = f2h(v);
}

// Build wT fp16 [L][2][j][k] from W_rel/W_root fp32 [L][k][j]
__global__ __launch_bounds__(128) void k_wprep(
    const float* __restrict__ W_rel, const float* __restrict__ W_root,
    _Float16* __restrict__ wT) {
    const int b = blockIdx.x;
    const int l = b >> 8;
    const int m = (b >> 7) & 1;
    const int j = b & 127;
    const int k = threadIdx.x;
    const float* W = (m == 0 ? W_rel : W_root) + (size_t)l * HID * HID;
    wT[(((size_t)l * 2 + m) * HID + j) * HID + k] = (_Float16)W[k * HID + j];
}

// ==================== CSR build: 2-pass LDS-staged bucket sort ====================

__global__ __launch_bounds__(256) void k_zeroB(int* __restrict__ b) { b[threadIdx.x] = 0; }

__global__ __launch_bounds__(256) void k_hist1(const int* __restrict__ dst,
                                               int* __restrict__ bhist) {
    __shared__ int h[NBUCK];
    h[threadIdx.x] = 0;
    __syncthreads();
    int stride = gridDim.x * blockDim.x;
    for (int e = blockIdx.x * 256 + threadIdx.x; e < N_EDGES_C; e += stride)
        atomicAdd(&h[dst[e] / BSZ], 1);
    __syncthreads();
    if (h[threadIdx.x]) atomicAdd(&bhist[threadIdx.x], h[threadIdx.x]);
}

__global__ __launch_bounds__(256) void k_bscan(const int* __restrict__ bhist,
                                               int* __restrict__ bbase,
                                               int* __restrict__ bcursor) {
    __shared__ int s[NBUCK];
    const int tid = threadIdx.x;
    int v = bhist[tid];
    s[tid] = v;
    __syncthreads();
    for (int off = 1; off < NBUCK; off <<= 1) {
        int t = (tid >= off) ? s[tid - off] : 0;
        __syncthreads();
        s[tid] += t;
        __syncthreads();
    }
    int excl = s[tid] - v;
    bbase[tid] = excl;
    bcursor[tid] = excl;
    if (tid == NBUCK - 1) bbase[NBUCK] = N_EDGES_C;
}

__global__ __launch_bounds__(256) void k_scatter1(
    const int* __restrict__ src, const int* __restrict__ dst,
    int* __restrict__ bcursor, unsigned* __restrict__ tmp) {
    __shared__ int h[NBUCK], sc[NBUCK], gb[NBUCK], lc[NBUCK];
    __shared__ unsigned lbuf[CHUNK];
    const int tid = threadIdx.x;
    const int base = blockIdx.x * CHUNK;
    h[tid] = 0; lc[tid] = 0;
    __syncthreads();
    unsigned rec[EPT]; int bk[EPT];
#pragma unroll
    for (int i = 0; i < EPT; ++i) {
        int e = base + i * 256 + tid;
        if (e < N_EDGES_C) {
            int d = dst[e];
            int b = d / BSZ;
            rec[i] = ((unsigned)src[e] << 9) | (unsigned)(d - b * BSZ);
            bk[i] = b;
            atomicAdd(&h[b], 1);
        } else bk[i] = -1;
    }
    __syncthreads();
    int v = h[tid];
    sc[tid] = v;
    __syncthreads();
    for (int off = 1; off < NBUCK; off <<= 1) {
        int t = (tid >= off) ? sc[tid - off] : 0;
        __syncthreads();
        sc[tid] += t;
        __syncthreads();
    }
    int excl = sc[tid] - v;
    gb[tid] = v ? atomicAdd(&bcursor[tid], v) : 0;
    sc[tid] = excl;
    __syncthreads();
#pragma unroll
    for (int i = 0; i < EPT; ++i) {
        if (bk[i] >= 0) {
            int p = atomicAdd(&lc[bk[i]], 1);
            lbuf[sc[bk[i]] + p] = rec[i];
        }
    }
    __syncthreads();
    const int wid = tid >> 6, lane = tid & 63;
    for (int b = wid; b < NBUCK; b += 4) {
        int n = h[b], g = gb[b], l = sc[b];
        for (int i = lane; i < n; i += 64) tmp[g + i] = lbuf[l + i];
    }
}

__global__ __launch_bounds__(256) void k_sort2(
    const unsigned* __restrict__ tmp, const int* __restrict__ bbase,
    int* __restrict__ offsets, int* __restrict__ es) {
    __shared__ int h[512], s2[512], cur[512];
    __shared__ int lbuf[BCAP];
    const int b = blockIdx.x, tid = threadIdx.x;
    const int base = bbase[b];
    const int cnt = bbase[b + 1] - base;
    h[tid] = 0; h[tid + 256] = 0;
    __syncthreads();
    for (int i = tid; i < cnt; i += 256) atomicAdd(&h[tmp[base + i] & 511], 1);
    __syncthreads();
    int v0 = h[tid], v1 = h[tid + 256];
    s2[tid] = v0; s2[tid + 256] = v1;
    __syncthreads();
    for (int off = 1; off < 512; off <<= 1) {
        int t0 = (tid >= off) ? s2[tid - off] : 0;
        int t1 = (tid + 256 >= off) ? s2[tid + 256 - off] : 0;
        __syncthreads();
        s2[tid] += t0; s2[tid + 256] += t1;
        __syncthreads();
    }
    int e0 = s2[tid] - v0, e1 = s2[tid + 256] - v1;
    cur[tid] = e0; cur[tid + 256] = e1;
    {
        int gn0 = b * BSZ + tid;
        if (tid < BSZ && gn0 < N_NODES_C) offsets[gn0] = base + e0;
        int n1 = tid + 256;
        int gn1 = b * BSZ + n1;
        if (n1 < BSZ && gn1 < N_NODES_C) offsets[gn1] = base + e1;
    }
    __syncthreads();
    for (int i = tid; i < cnt; i += 256) {
        unsigned r = tmp[base + i];
        int ld = r & 511;
        int p = atomicAdd(&cur[ld], 1);
        lbuf[p] = (int)(r >> 9);
    }
    __syncthreads();
    for (int i = tid; i < cnt; i += 256) es[base + i] = lbuf[i];
    if (b == NBUCK - 1 && tid == 0) offsets[N_NODES_C] = N_EDGES_C;
}

// ==================== layers ====================

// Gather-sum: one 32-lane group per node. Block b owns granule b (nodes 8b..8b+7)
// -> writes agg granule b on XCD b%8 (round-robin dispatch).
__global__ __launch_bounds__(256) void k_gather(
    const _Float16* __restrict__ h_in, _Float16* __restrict__ agg,
    const int* __restrict__ offsets, const int* __restrict__ es) {
    const int node = (blockIdx.x << 3) + (threadIdx.x >> 5);
    const int lane = threadIdx.x & 31;
    const int c4 = lane * 4;
    const int beg = offsets[node];
    const int end = offsets[node + 1];
    f4 a0 = {0.f, 0.f, 0.f, 0.f}, a1 = a0, a2 = a0, a3 = a0;
    f4 a4 = a0, a5 = a0, a6 = a0, a7 = a0;
    int e = beg;
    for (; e + 8 <= end; e += 8) {
        int s0 = es[e],     s1 = es[e + 1], s2 = es[e + 2], s3 = es[e + 3];
        int s4 = es[e + 4], s5 = es[e + 5], s6 = es[e + 6], s7 = es[e + 7];
        h4 v0 = *(const h4*)(h_in + (size_t)s0 * HID + c4);
        h4 v1 = *(const h4*)(h_in + (size_t)s1 * HID + c4);
        h4 v2 = *(const h4*)(h_in + (size_t)s2 * HID + c4);
        h4 v3 = *(const h4*)(h_in + (size_t)s3 * HID + c4);
        h4 v4 = *(const h4*)(h_in + (size_t)s4 * HID + c4);
        h4 v5 = *(const h4*)(h_in + (size_t)s5 * HID + c4);
        h4 v6 = *(const h4*)(h_in + (size_t)s6 * HID + c4);
        h4 v7 = *(const h4*)(h_in + (size_t)s7 * HID + c4);
        a0 += h2f(v0); a1 += h2f(v1); a2 += h2f(v2); a3 += h2f(v3);
        a4 += h2f(v4); a5 += h2f(v5); a6 += h2f(v6); a7 += h2f(v7);
    }
    for (; e + 4 <= end; e += 4) {
        int s0 = es[e], s1 = es[e + 1], s2 = es[e + 2], s3 = es[e + 3];
        h4 v0 = *(const h4*)(h_in + (size_t)s0 * HID + c4);
        h4 v1 = *(const h4*)(h_in + (size_t)s1 * HID + c4);
        h4 v2 = *(const h4*)(h_in + (size_t)s2 * HID + c4);
        h4 v3 = *(const h4*)(h_in + (size_t)s3 * HID + c4);
        a0 += h2f(v0); a1 += h2f(v1); a2 += h2f(v2); a3 += h2f(v3);
    }
    for (; e < end; ++e)
        a0 += h2f(*(const h4*)(h_in + (size_t)es[e] * HID + c4));
    f4 t = ((a0 + a1) + (a2 + a3)) + ((a4 + a5) + (a6 + a7));
    *(h4*)(agg + (size_t)node * HID + c4) = f2h(t);
}

// MFMA GEMM, XCD-aligned: block -> XCD blockIdx&7; wave owns (jt, chunk) and
// loops ~6 tiles whose 16 rows = granule pair {xcd+16t, xcd+16t+8} (all == xcd
// mod 8) -> A/H reads and h_out stores hit the LOCAL per-XCD L2 where k_gather/
// previous gemm wrote them (dirty-line cross-XCD read was the r14-r18 62us
// plateau hypothesis; FETCH_SIZE drop will confirm/refute).
__global__ __launch_bounds__(128) void k_gemm_mfma(
    const _Float16* __restrict__ agg, const _Float16* __restrict__ h_in,
    _Float16* __restrict__ h_out,
    const _Float16* __restrict__ wT,   // [2][HID][HID] (j,k) for this layer
    const float* __restrict__ b_rel) {
    const int lane = threadIdx.x & 63;
    const int wv = threadIdx.x >> 6;               // 0..1
    const int xcd = blockIdx.x & 7;
    const int idx = ((blockIdx.x >> 3) << 1) | wv; // 0..1023
    const int jt = idx >> 7;                       // 0..7
    const int chunk = idx & 127;                   // 0..127
    const int t0 = (chunk * TPX) >> 7;
    const int t1 = ((chunk + 1) * TPX) >> 7;
    const int row = lane & 15;
    const int kg = lane >> 4;                      // 0..3
    const int j = (jt << 4) + row;
    const float b = b_rel[j];

    const _Float16* wrP = wT + (size_t)j * HID + (kg << 3);
    const _Float16* woP = wT + (size_t)(HID + j) * HID + (kg << 3);
    const f16x8 bR0 = *(const f16x8*)(wrP + 0);
    const f16x8 bR1 = *(const f16x8*)(wrP + 32);
    const f16x8 bR2 = *(const f16x8*)(wrP + 64);
    const f16x8 bR3 = *(const f16x8*)(wrP + 96);
    const f16x8 bO0 = *(const f16x8*)(woP + 0);
    const f16x8 bO1 = *(const f16x8*)(woP + 32);
    const f16x8 bO2 = *(const f16x8*)(woP + 64);
    const f16x8 bO3 = *(const f16x8*)(woP + 96);

    // node for output-row rr (0..15) of tile t: rows 0-7 -> granule xcd+16t,
    // rows 8-15 -> granule xcd+16t+8
    auto nodeOf = [&](int t, int rr) -> int {
        int g1 = xcd + (t << 4);
        return (rr < 8) ? ((g1 << 3) + rr) : (((g1 + 8) << 3) + (rr - 8));
    };
    auto aBase = [&](int t) -> const _Float16* {
        int n = nodeOf(t, row);
        if (n >= N_NODES_C) n = N_NODES_C - 1;  // clamped load, store guarded
        return agg + (size_t)n * HID + (kg << 3);
    };
    auto hBase = [&](int t) -> const _Float16* {
        int n = nodeOf(t, row);
        if (n >= N_NODES_C) n = N_NODES_C - 1;
        return h_in + (size_t)n * HID + (kg << 3);
    };

    const _Float16* aP = aBase(t0);
    const _Float16* hP = hBase(t0);
    f16x8 cA0 = *(const f16x8*)(aP + 0),  cA1 = *(const f16x8*)(aP + 32);
    f16x8 cA2 = *(const f16x8*)(aP + 64), cA3 = *(const f16x8*)(aP + 96);
    f16x8 cH0 = *(const f16x8*)(hP + 0),  cH1 = *(const f16x8*)(hP + 32);
    f16x8 cH2 = *(const f16x8*)(hP + 64), cH3 = *(const f16x8*)(hP + 96);

    for (int t = t0; t < t1; ++t) {
        f16x8 nA0, nA1, nA2, nA3, nH0, nH1, nH2, nH3;
        if (t + 1 < t1) {
            const _Float16* aN = aBase(t + 1);
            const _Float16* hN = hBase(t + 1);
            nA0 = *(const f16x8*)(aN + 0);  nA1 = *(const f16x8*)(aN + 32);
            nA2 = *(const f16x8*)(aN + 64); nA3 = *(const f16x8*)(aN + 96);
            nH0 = *(const f16x8*)(hN + 0);  nH1 = *(const f16x8*)(hN + 32);
            nH2 = *(const f16x8*)(hN + 64); nH3 = *(const f16x8*)(hN + 96);
        }
        f32x4 acc1 = {0.f, 0.f, 0.f, 0.f}, acc2 = acc1;
        acc1 = __builtin_amdgcn_mfma_f32_16x16x32_f16(cA0, bR0, acc1, 0, 0, 0);
        acc2 = __builtin_amdgcn_mfma_f32_16x16x32_f16(cA2, bR2, acc2, 0, 0, 0);
        acc1 = __builtin_amdgcn_mfma_f32_16x16x32_f16(cH0, bO0, acc1, 0, 0, 0);
        acc2 = __builtin_amdgcn_mfma_f32_16x16x32_f16(cH2, bO2, acc2, 0, 0, 0);
        acc1 = __builtin_amdgcn_mfma_f32_16x16x32_f16(cA1, bR1, acc1, 0, 0, 0);
        acc2 = __builtin_amdgcn_mfma_f32_16x16x32_f16(cA3, bR3, acc2, 0, 0, 0);
        acc1 = __builtin_amdgcn_mfma_f32_16x16x32_f16(cH1, bO1, acc1, 0, 0, 0);
        acc2 = __builtin_amdgcn_mfma_f32_16x16x32_f16(cH3, bO3, acc2, 0, 0, 0);
        const f32x4 acc = acc1 + acc2;
#pragma unroll
        for (int r = 0; r < 4; ++r) {
            int rr = (kg << 2) + r;
            int n = nodeOf(t, rr);
            if (n < N_NODES_C) {
                float v = atanf(acc[r] + b);
                h_out[(size_t)n * HID + j] = (_Float16)v;
            }
        }
        cA0 = nA0; cA1 = nA1; cA2 = nA2; cA3 = nA3;
        cH0 = nH0; cH1 = nH1; cH2 = nH2; cH3 = nH3;
    }
}

// Pool stage 1: per (graph, segment) partial sums over fp16 h -> fp32 part
__global__ __launch_bounds__(256) void k_pool1(
    const _Float16* __restrict__ h, const int* __restrict__ batch,
    float* __restrict__ part) {
    __shared__ float sm[2][HID];
    const int b = blockIdx.x;
    const int g = b >> 3, s = b & (SEG - 1);
    const int j = threadIdx.x & 127;
    const int half = threadIdx.x >> 7;

    int lo = 0, hi = N_NODES_C;
    while (lo < hi) { int mid = (lo + hi) >> 1; if (batch[mid] < g) lo = mid + 1; else hi = mid; }
    int start = lo;
    hi = N_NODES_C;
    while (lo < hi) { int mid = (lo + hi) >> 1; if (batch[mid] < g + 1) lo = mid + 1; else hi = mid; }
    int end = lo;
    int len = end - start;
    int s0 = start + (int)((long long)len * s / SEG);
    int s1 = start + (int)((long long)len * (s + 1) / SEG);

    float acc = 0.f;
    for (int i = s0 + half; i < s1; i += 2) acc += (float)h[(size_t)i * HID + j];
    sm[half][j] = acc;
    __syncthreads();
    if (threadIdx.x < HID) part[(size_t)b * HID + j] = sm[0][j] + sm[1][j];
}

// Pool stage 2 + head
__global__ __launch_bounds__(128) void k_head(
    const float* __restrict__ part, const float* __restrict__ W_out,
    const float* __restrict__ b_out, float* __restrict__ out) {
    __shared__ float sf[HID];
    const int g = blockIdx.x;
    const int j = threadIdx.x;
    float v = 0.f;
    for (int s = 0; s < SEG; ++s) v += part[(size_t)(g * SEG + s) * HID + j];
    sf[j] = v;
    __syncthreads();
    if (j < OUTD) {
        float a = b_out[j];
        for (int k = 0; k < HID; ++k) a += sf[k] * W_out[k * OUTD + j];
        out[g * OUTD + j] = 1.f / (1.f + expf(-a));
    }
}

extern "C" void kernel_launch(void* const* d_in, const int* in_sizes, int n_in,
                              void* d_out, int out_size, void* d_ws, size_t ws_size,
                              hipStream_t stream) {
    const float* x      = (const float*)d_in[0];
    const int*   ei     = (const int*)d_in[1];
    const int*   src    = ei;
    const int*   dst    = ei + N_EDGES_C;
    const int*   batch  = (const int*)d_in[2];
    const float* W_rel  = (const float*)d_in[3];
    const float* b_rel  = (const float*)d_in[4];
    const float* W_root = (const float*)d_in[5];
    const float* W_out  = (const float*)d_in[6];
    const float* b_out  = (const float*)d_in[7];
    float* out = (float*)d_out;

    char* ws = (char*)d_ws;
    size_t off = 0;
    auto alloc = [&](size_t bytes) { void* p = ws + off; off = align_up(off + bytes, 256); return p; };
    _Float16* xh    = (_Float16*)alloc((size_t)N_NODES_C * HID * 2);
    _Float16* h1h   = (_Float16*)alloc((size_t)N_NODES_C * HID * 2);
    _Float16* agg16 = (_Float16*)alloc((size_t)N_NODES_C * HID * 2);
    _Float16* wT    = (_Float16*)alloc((size_t)3 * 2 * HID * HID * 2);
    int*   offsets = (int*)alloc((size_t)(N_NODES_C + 1) * sizeof(int));
    int*   es      = (int*)alloc((size_t)N_EDGES_C * sizeof(int));
    unsigned* tmp  = (unsigned*)alloc((size_t)N_EDGES_C * sizeof(unsigned));
    int*   bhist   = (int*)alloc(NBUCK * sizeof(int));
    int*   bbase   = (int*)alloc((NBUCK + 1) * sizeof(int));
    int*   bcursor = (int*)alloc(NBUCK * sizeof(int));
    float* part    = (float*)alloc((size_t)N_GRAPHS_C * SEG * HID * sizeof(float));

    const int gather_blocks = N_NODES_C / 8;          // 12500
    const int mfma_blocks = 4096;                     // 8 xcd x 512 wave-pairs (128 thr)
    const int scat_blocks = (N_EDGES_C + CHUNK - 1) / CHUNK;
    const size_t WTL = (size_t)2 * HID * HID;

    // ---- weight prep + x -> fp16 ----
    k_wprep<<<768, 128, 0, stream>>>(W_rel, W_root, wT);
    k_cvt<<<(N_NODES_C * HID) / 4 / 256, 256, 0, stream>>>(x, xh);

    // ---- CSR build: bucket sort, all global scatter staged through LDS ----
    k_zeroB<<<1, 256, 0, stream>>>(bhist);
    k_hist1<<<1024, 256, 0, stream>>>(dst, bhist);
    k_bscan<<<1, 256, 0, stream>>>(bhist, bbase, bcursor);
    k_scatter1<<<scat_blocks, 256, 0, stream>>>(src, dst, bcursor, tmp);
    k_sort2<<<NBUCK, 256, 0, stream>>>(tmp, bbase, offsets, es);

    // ---- 3 GraphConv layers: gather (latency-opt) + MFMA gemm (XCD-aligned) ----
    k_gather<<<gather_blocks, 256, 0, stream>>>(xh, agg16, offsets, es);
    k_gemm_mfma<<<mfma_blocks, 128, 0, stream>>>(agg16, xh, h1h, wT + 0 * WTL, b_rel + 0 * HID);
    k_gather<<<gather_blocks, 256, 0, stream>>>(h1h, agg16, offsets, es);
    k_gemm_mfma<<<mfma_blocks, 128, 0, stream>>>(agg16, h1h, xh, wT + 1 * WTL, b_rel + 1 * HID);
    k_gather<<<gather_blocks, 256, 0, stream>>>(xh, agg16, offsets, es);
    k_gemm_mfma<<<mfma_blocks, 128, 0, stream>>>(agg16, xh, h1h, wT + 2 * WTL, b_rel + 2 * HID);

    // ---- pool + head ----
    k_pool1<<<N_GRAPHS_C * SEG, 256, 0, stream>>>(h1h, batch, part);
    k_head<<<N_GRAPHS_C, 128, 0, stream>>>(part, W_out, b_out, out);
}

// Round 21
// 395.260 us; speedup vs baseline: 1.2270x; 1.2033x over previous
//
#include <hip/hip_runtime.h>
#include <hip/hip_bf16.h>

#define N_NODES_C 100000
#define N_EDGES_C 1600000
#define HID 128
#define OUTD 8
#define N_GRAPHS_C 128
#define SEG 8     // pool segments per graph
#define NBUCK 256 // CSR sort buckets
#define BSZ 391   // nodes per bucket
#define BCAP 8192
#define CHUNK 2048
#define EPT 8
#define GT 64     // nodes per gemm tile
#define GTILES ((N_NODES_C + GT - 1) / GT)  // 1563
#define GBLOCKS 256

typedef __attribute__((ext_vector_type(4))) float f4;
typedef __attribute__((ext_vector_type(4))) _Float16 h4;
typedef __attribute__((ext_vector_type(8))) _Float16 f16x8;
typedef __attribute__((ext_vector_type(4))) float f32x4;

static inline size_t align_up(size_t x, size_t a) { return (x + a - 1) & ~(a - 1); }

__device__ __forceinline__ f4 h2f(h4 v) { return __builtin_convertvector(v, f4); }
__device__ __forceinline__ h4 f2h(f4 v) { return __builtin_convertvector(v, h4); }

__global__ __launch_bounds__(256) void k_cvt(const float* __restrict__ in,
                                             _Float16* __restrict__ out) {
    int i = blockIdx.x * blockDim.x + threadIdx.x;
    f4 v = *(const f4*)(in + (size_t)i * 4);
    *(h4*)(out + (size_t)i * 4) = f2h(v);
}

// Build wT fp16 [L][2][j][k] from W_rel/W_root fp32 [L][k][j]
__global__ __launch_bounds__(128) void k_wprep(
    const float* __restrict__ W_rel, const float* __restrict__ W_root,
    _Float16* __restrict__ wT) {
    const int b = blockIdx.x;
    const int l = b >> 8;
    const int m = (b >> 7) & 1;
    const int j = b & 127;
    const int k = threadIdx.x;
    const float* W = (m == 0 ? W_rel : W_root) + (size_t)l * HID * HID;
    wT[(((size_t)l * 2 + m) * HID + j) * HID + k] = (_Float16)W[k * HID + j];
}

// ==================== CSR build: 2-pass LDS-staged bucket sort ====================

__global__ __launch_bounds__(256) void k_zeroB(int* __restrict__ b) { b[threadIdx.x] = 0; }

__global__ __launch_bounds__(256) void k_hist1(const int* __restrict__ dst,
                                               int* __restrict__ bhist) {
    __shared__ int h[NBUCK];
    h[threadIdx.x] = 0;
    __syncthreads();
    int stride = gridDim.x * blockDim.x;
    for (int e = blockIdx.x * 256 + threadIdx.x; e < N_EDGES_C; e += stride)
        atomicAdd(&h[dst[e] / BSZ], 1);
    __syncthreads();
    if (h[threadIdx.x]) atomicAdd(&bhist[threadIdx.x], h[threadIdx.x]);
}

__global__ __launch_bounds__(256) void k_bscan(const int* __restrict__ bhist,
                                               int* __restrict__ bbase,
                                               int* __restrict__ bcursor) {
    __shared__ int s[NBUCK];
    const int tid = threadIdx.x;
    int v = bhist[tid];
    s[tid] = v;
    __syncthreads();
    for (int off = 1; off < NBUCK; off <<= 1) {
        int t = (tid >= off) ? s[tid - off] : 0;
        __syncthreads();
        s[tid] += t;
        __syncthreads();
    }
    int excl = s[tid] - v;
    bbase[tid] = excl;
    bcursor[tid] = excl;
    if (tid == NBUCK - 1) bbase[NBUCK] = N_EDGES_C;
}

__global__ __launch_bounds__(256) void k_scatter1(
    const int* __restrict__ src, const int* __restrict__ dst,
    int* __restrict__ bcursor, unsigned* __restrict__ tmp) {
    __shared__ int h[NBUCK], sc[NBUCK], gb[NBUCK], lc[NBUCK];
    __shared__ unsigned lbuf[CHUNK];
    const int tid = threadIdx.x;
    const int base = blockIdx.x * CHUNK;
    h[tid] = 0; lc[tid] = 0;
    __syncthreads();
    unsigned rec[EPT]; int bk[EPT];
#pragma unroll
    for (int i = 0; i < EPT; ++i) {
        int e = base + i * 256 + tid;
        if (e < N_EDGES_C) {
            int d = dst[e];
            int b = d / BSZ;
            rec[i] = ((unsigned)src[e] << 9) | (unsigned)(d - b * BSZ);
            bk[i] = b;
            atomicAdd(&h[b], 1);
        } else bk[i] = -1;
    }
    __syncthreads();
    int v = h[tid];
    sc[tid] = v;
    __syncthreads();
    for (int off = 1; off < NBUCK; off <<= 1) {
        int t = (tid >= off) ? sc[tid - off] : 0;
        __syncthreads();
        sc[tid] += t;
        __syncthreads();
    }
    int excl = sc[tid] - v;
    gb[tid] = v ? atomicAdd(&bcursor[tid], v) : 0;
    sc[tid] = excl;
    __syncthreads();
#pragma unroll
    for (int i = 0; i < EPT; ++i) {
        if (bk[i] >= 0) {
            int p = atomicAdd(&lc[bk[i]], 1);
            lbuf[sc[bk[i]] + p] = rec[i];
        }
    }
    __syncthreads();
    const int wid = tid >> 6, lane = tid & 63;
    for (int b = wid; b < NBUCK; b += 4) {
        int n = h[b], g = gb[b], l = sc[b];
        for (int i = lane; i < n; i += 64) tmp[g + i] = lbuf[l + i];
    }
}

__global__ __launch_bounds__(256) void k_sort2(
    const unsigned* __restrict__ tmp, const int* __restrict__ bbase,
    int* __restrict__ offsets, int* __restrict__ es) {
    __shared__ int h[512], s2[512], cur[512];
    __shared__ int lbuf[BCAP];
    const int b = blockIdx.x, tid = threadIdx.x;
    const int base = bbase[b];
    const int cnt = bbase[b + 1] - base;
    h[tid] = 0; h[tid + 256] = 0;
    __syncthreads();
    for (int i = tid; i < cnt; i += 256) atomicAdd(&h[tmp[base + i] & 511], 1);
    __syncthreads();
    int v0 = h[tid], v1 = h[tid + 256];
    s2[tid] = v0; s2[tid + 256] = v1;
    __syncthreads();
    for (int off = 1; off < 512; off <<= 1) {
        int t0 = (tid >= off) ? s2[tid - off] : 0;
        int t1 = (tid + 256 >= off) ? s2[tid + 256 - off] : 0;
        __syncthreads();
        s2[tid] += t0; s2[tid + 256] += t1;
        __syncthreads();
    }
    int e0 = s2[tid] - v0, e1 = s2[tid + 256] - v1;
    cur[tid] = e0; cur[tid + 256] = e1;
    {
        int gn0 = b * BSZ + tid;
        if (tid < BSZ && gn0 < N_NODES_C) offsets[gn0] = base + e0;
        int n1 = tid + 256;
        int gn1 = b * BSZ + n1;
        if (n1 < BSZ && gn1 < N_NODES_C) offsets[gn1] = base + e1;
    }
    __syncthreads();
    for (int i = tid; i < cnt; i += 256) {
        unsigned r = tmp[base + i];
        int ld = r & 511;
        int p = atomicAdd(&cur[ld], 1);
        lbuf[p] = (int)(r >> 9);
    }
    __syncthreads();
    for (int i = tid; i < cnt; i += 256) es[base + i] = lbuf[i];
    if (b == NBUCK - 1 && tid == 0) offsets[N_NODES_C] = N_EDGES_C;
}

// ==================== layers ====================

// Gather-sum: one 32-lane group per node. No LDS, no barriers -> max TLP.
__global__ __launch_bounds__(256) void k_gather(
    const _Float16* __restrict__ h_in, _Float16* __restrict__ agg,
    const int* __restrict__ offsets, const int* __restrict__ es) {
    const int node = (blockIdx.x << 3) + (threadIdx.x >> 5);
    const int lane = threadIdx.x & 31;
    const int c4 = lane * 4;
    const int beg = offsets[node];
    const int end = offsets[node + 1];
    f4 a0 = {0.f, 0.f, 0.f, 0.f}, a1 = a0, a2 = a0, a3 = a0;
    f4 a4 = a0, a5 = a0, a6 = a0, a7 = a0;
    int e = beg;
    for (; e + 8 <= end; e += 8) {
        int s0 = es[e],     s1 = es[e + 1], s2 = es[e + 2], s3 = es[e + 3];
        int s4 = es[e + 4], s5 = es[e + 5], s6 = es[e + 6], s7 = es[e + 7];
        h4 v0 = *(const h4*)(h_in + (size_t)s0 * HID + c4);
        h4 v1 = *(const h4*)(h_in + (size_t)s1 * HID + c4);
        h4 v2 = *(const h4*)(h_in + (size_t)s2 * HID + c4);
        h4 v3 = *(const h4*)(h_in + (size_t)s3 * HID + c4);
        h4 v4 = *(const h4*)(h_in + (size_t)s4 * HID + c4);
        h4 v5 = *(const h4*)(h_in + (size_t)s5 * HID + c4);
        h4 v6 = *(const h4*)(h_in + (size_t)s6 * HID + c4);
        h4 v7 = *(const h4*)(h_in + (size_t)s7 * HID + c4);
        a0 += h2f(v0); a1 += h2f(v1); a2 += h2f(v2); a3 += h2f(v3);
        a4 += h2f(v4); a5 += h2f(v5); a6 += h2f(v6); a7 += h2f(v7);
    }
    for (; e + 4 <= end; e += 4) {
        int s0 = es[e], s1 = es[e + 1], s2 = es[e + 2], s3 = es[e + 3];
        h4 v0 = *(const h4*)(h_in + (size_t)s0 * HID + c4);
        h4 v1 = *(const h4*)(h_in + (size_t)s1 * HID + c4);
        h4 v2 = *(const h4*)(h_in + (size_t)s2 * HID + c4);
        h4 v3 = *(const h4*)(h_in + (size_t)s3 * HID + c4);
        a0 += h2f(v0); a1 += h2f(v1); a2 += h2f(v2); a3 += h2f(v3);
    }
    for (; e < end; ++e)
        a0 += h2f(*(const h4*)(h_in + (size_t)es[e] * HID + c4));
    f4 t = ((a0 + a1) + (a2 + a3)) + ((a4 + a5) + (a6 + a7));
    *(h4*)(agg + (size_t)node * HID + c4) = f2h(t);
}

// MFMA GEMM, LDS-staged (sec-5 pattern). r19 evidence: time invariant (62us)
// across occupancy/traffic variants -> L2 TRANSACTION bound: fragment loads hit
// 16x 64B segments per instruction. Fix: stage A/H tiles via COALESCED global
// loads (lane i <- base + i*16B: 4 contiguous rows/inst), redistribute to
// fragment layout via ds_read_b128 with XOR seg-swizzle (both sides; 2-way
// conflict = free). W in registers (2 j-tiles/wave), grid loops tiles.
__global__ __launch_bounds__(256) void k_gemm_mfma(
    const _Float16* __restrict__ agg, const _Float16* __restrict__ h_in,
    _Float16* __restrict__ h_out,
    const _Float16* __restrict__ wT,   // [2][HID][HID] (j,k) for this layer
    const float* __restrict__ b_rel) {
    __shared__ _Float16 ldsA[GT * HID];  // 16 KB, seg-swizzled
    __shared__ _Float16 ldsH[GT * HID];  // 16 KB
    const int tid = threadIdx.x;
    const int lane = tid & 63;
    const int wv = tid >> 6;        // 0..3
    const int row16 = lane & 15;
    const int kg = lane >> 4;       // 0..3

    // W fragments for j-tile pair {2wv, 2wv+1}: 16 f16x8 = 64 VGPR, loaded once
    f16x8 WR[2][4], WO[2][4];
    float bb[2];
#pragma unroll
    for (int p = 0; p < 2; ++p) {
        const int j = ((2 * wv + p) << 4) + row16;
        const _Float16* wr = wT + (size_t)j * HID + (kg << 3);
        const _Float16* wo = wT + (size_t)(HID + j) * HID + (kg << 3);
#pragma unroll
        for (int s = 0; s < 4; ++s) {
            WR[p][s] = *(const f16x8*)(wr + s * 32);
            WO[p][s] = *(const f16x8*)(wo + s * 32);
        }
        bb[p] = b_rel[j];
    }

    for (int t = blockIdx.x; t < GTILES; t += GBLOCKS) {
        const int n0 = t * GT;
        __syncthreads();  // protect previous iteration's LDS reads
        // stage A/H: 1024 segs x 16B each; 256 threads x 4 rounds; coalesced
#pragma unroll
        for (int rnd = 0; rnd < 4; ++rnd) {
            const int idx = rnd * 256 + tid;  // 0..1023
            const int r = idx >> 4;           // row 0..63
            const int s = idx & 15;           // seg 0..15
            int n = n0 + r;
            if (n >= N_NODES_C) n = N_NODES_C - 1;  // clamp (stores guarded)
            const int sp = s ^ (r & 7);             // XOR swizzle
            *(f16x8*)(ldsA + ((size_t)r * 16 + sp) * 8) =
                *(const f16x8*)(agg + (size_t)n * HID + s * 8);
            *(f16x8*)(ldsH + ((size_t)r * 16 + sp) * 8) =
                *(const f16x8*)(h_in + (size_t)n * HID + s * 8);
        }
        __syncthreads();
        // compute: 2 j-tiles x 4 node-subtiles per wave
#pragma unroll
        for (int p = 0; p < 2; ++p) {
            const int j = ((2 * wv + p) << 4) + row16;
#pragma unroll
            for (int nt = 0; nt < 4; ++nt) {
                const int r = nt * 16 + row16;  // A-row in tile
                f16x8 fA[4], fH[4];
#pragma unroll
                for (int s = 0; s < 4; ++s) {
                    const int sp = (s * 4 + kg) ^ (r & 7);
                    fA[s] = *(const f16x8*)(ldsA + ((size_t)r * 16 + sp) * 8);
                    fH[s] = *(const f16x8*)(ldsH + ((size_t)r * 16 + sp) * 8);
                }
                f32x4 a1 = {0.f, 0.f, 0.f, 0.f}, a2 = a1;
                a1 = __builtin_amdgcn_mfma_f32_16x16x32_f16(fA[0], WR[p][0], a1, 0, 0, 0);
                a2 = __builtin_amdgcn_mfma_f32_16x16x32_f16(fA[2], WR[p][2], a2, 0, 0, 0);
                a1 = __builtin_amdgcn_mfma_f32_16x16x32_f16(fH[0], WO[p][0], a1, 0, 0, 0);
                a2 = __builtin_amdgcn_mfma_f32_16x16x32_f16(fH[2], WO[p][2], a2, 0, 0, 0);
                a1 = __builtin_amdgcn_mfma_f32_16x16x32_f16(fA[1], WR[p][1], a1, 0, 0, 0);
                a2 = __builtin_amdgcn_mfma_f32_16x16x32_f16(fA[3], WR[p][3], a2, 0, 0, 0);
                a1 = __builtin_amdgcn_mfma_f32_16x16x32_f16(fH[1], WO[p][1], a1, 0, 0, 0);
                a2 = __builtin_amdgcn_mfma_f32_16x16x32_f16(fH[3], WO[p][3], a2, 0, 0, 0);
                const f32x4 acc = a1 + a2;
#pragma unroll
                for (int rr = 0; rr < 4; ++rr) {
                    const int n = n0 + nt * 16 + (kg << 2) + rr;
                    if (n < N_NODES_C)
                        h_out[(size_t)n * HID + j] = (_Float16)atanf(acc[rr] + bb[p]);
                }
            }
        }
    }
}

// Pool stage 1: per (graph, segment) partial sums over fp16 h -> fp32 part
__global__ __launch_bounds__(256) void k_pool1(
    const _Float16* __restrict__ h, const int* __restrict__ batch,
    float* __restrict__ part) {
    __shared__ float sm[2][HID];
    const int b = blockIdx.x;
    const int g = b >> 3, s = b & (SEG - 1);
    const int j = threadIdx.x & 127;
    const int half = threadIdx.x >> 7;

    int lo = 0, hi = N_NODES_C;
    while (lo < hi) { int mid = (lo + hi) >> 1; if (batch[mid] < g) lo = mid + 1; else hi = mid; }
    int start = lo;
    hi = N_NODES_C;
    while (lo < hi) { int mid = (lo + hi) >> 1; if (batch[mid] < g + 1) lo = mid + 1; else hi = mid; }
    int end = lo;
    int len = end - start;
    int s0 = start + (int)((long long)len * s / SEG);
    int s1 = start + (int)((long long)len * (s + 1) / SEG);

    float acc = 0.f;
    for (int i = s0 + half; i < s1; i += 2) acc += (float)h[(size_t)i * HID + j];
    sm[half][j] = acc;
    __syncthreads();
    if (threadIdx.x < HID) part[(size_t)b * HID + j] = sm[0][j] + sm[1][j];
}

// Pool stage 2 + head
__global__ __launch_bounds__(128) void k_head(
    const float* __restrict__ part, const float* __restrict__ W_out,
    const float* __restrict__ b_out, float* __restrict__ out) {
    __shared__ float sf[HID];
    const int g = blockIdx.x;
    const int j = threadIdx.x;
    float v = 0.f;
    for (int s = 0; s < SEG; ++s) v += part[(size_t)(g * SEG + s) * HID + j];
    sf[j] = v;
    __syncthreads();
    if (j < OUTD) {
        float a = b_out[j];
        for (int k = 0; k < HID; ++k) a += sf[k] * W_out[k * OUTD + j];
        out[g * OUTD + j] = 1.f / (1.f + expf(-a));
    }
}

extern "C" void kernel_launch(void* const* d_in, const int* in_sizes, int n_in,
                              void* d_out, int out_size, void* d_ws, size_t ws_size,
                              hipStream_t stream) {
    const float* x      = (const float*)d_in[0];
    const int*   ei     = (const int*)d_in[1];
    const int*   src    = ei;
    const int*   dst    = ei + N_EDGES_C;
    const int*   batch  = (const int*)d_in[2];
    const float* W_rel  = (const float*)d_in[3];
    const float* b_rel  = (const float*)d_in[4];
    const float* W_root = (const float*)d_in[5];
    const float* W_out  = (const float*)d_in[6];
    const float* b_out  = (const float*)d_in[7];
    float* out = (float*)d_out;

    char* ws = (char*)d_ws;
    size_t off = 0;
    auto alloc = [&](size_t bytes) { void* p = ws + off; off = align_up(off + bytes, 256); return p; };
    _Float16* xh    = (_Float16*)alloc((size_t)N_NODES_C * HID * 2);
    _Float16* h1h   = (_Float16*)alloc((size_t)N_NODES_C * HID * 2);
    _Float16* agg16 = (_Float16*)alloc((size_t)N_NODES_C * HID * 2);
    _Float16* wT    = (_Float16*)alloc((size_t)3 * 2 * HID * HID * 2);
    int*   offsets = (int*)alloc((size_t)(N_NODES_C + 1) * sizeof(int));
    int*   es      = (int*)alloc((size_t)N_EDGES_C * sizeof(int));
    unsigned* tmp  = (unsigned*)alloc((size_t)N_EDGES_C * sizeof(unsigned));
    int*   bhist   = (int*)alloc(NBUCK * sizeof(int));
    int*   bbase   = (int*)alloc((NBUCK + 1) * sizeof(int));
    int*   bcursor = (int*)alloc(NBUCK * sizeof(int));
    float* part    = (float*)alloc((size_t)N_GRAPHS_C * SEG * HID * sizeof(float));

    const int gather_blocks = N_NODES_C / 8;          // 12500
    const int scat_blocks = (N_EDGES_C + CHUNK - 1) / CHUNK;
    const size_t WTL = (size_t)2 * HID * HID;

    // ---- weight prep + x -> fp16 ----
    k_wprep<<<768, 128, 0, stream>>>(W_rel, W_root, wT);
    k_cvt<<<(N_NODES_C * HID) / 4 / 256, 256, 0, stream>>>(x, xh);

    // ---- CSR build: bucket sort, all global scatter staged through LDS ----
    k_zeroB<<<1, 256, 0, stream>>>(bhist);
    k_hist1<<<1024, 256, 0, stream>>>(dst, bhist);
    k_bscan<<<1, 256, 0, stream>>>(bhist, bbase, bcursor);
    k_scatter1<<<scat_blocks, 256, 0, stream>>>(src, dst, bcursor, tmp);
    k_sort2<<<NBUCK, 256, 0, stream>>>(tmp, bbase, offsets, es);

    // ---- 3 GraphConv layers: gather (latency-opt) + MFMA gemm (LDS-staged) ----
    k_gather<<<gather_blocks, 256, 0, stream>>>(xh, agg16, offsets, es);
    k_gemm_mfma<<<GBLOCKS, 256, 0, stream>>>(agg16, xh, h1h, wT + 0 * WTL, b_rel + 0 * HID);
    k_gather<<<gather_blocks, 256, 0, stream>>>(h1h, agg16, offsets, es);
    k_gemm_mfma<<<GBLOCKS, 256, 0, stream>>>(agg16, h1h, xh, wT + 1 * WTL, b_rel + 1 * HID);
    k_gather<<<gather_blocks, 256, 0, stream>>>(xh, agg16, offsets, es);
    k_gemm_mfma<<<GBLOCKS, 256, 0, stream>>>(agg16, xh, h1h, wT + 2 * WTL, b_rel + 2 * HID);

    // ---- pool + head ----
    k_pool1<<<N_GRAPHS_C * SEG, 256, 0, stream>>>(h1h, batch, part);
    k_head<<<N_GRAPHS_C, 128, 0, stream>>>(part, W_out, b_out, out);
}

// Round 23
// 391.748 us; speedup vs baseline: 1.2380x; 1.0090x over previous
//
#include <hip/hip_runtime.h>
#include <hip/hip_bf16.h>

#define N_NODES_C 100000
#define N_EDGES_C 1600000
#define HID 128
#define OUTD 8
#define N_GRAPHS_C 128
#define SEG 8     // pool segments per graph
#define NBUCK 256 // CSR sort buckets
#define BSZ 391   // nodes per bucket
#define BCAP 8192
#define CHUNK 4096
#define EPT 16
#define GT 64     // nodes per gemm tile
#define GTILES ((N_NODES_C + GT - 1) / GT)  // 1563
#define GBLOCKS 256

typedef __attribute__((ext_vector_type(4))) float f4;
typedef __attribute__((ext_vector_type(8))) float f32x8;
typedef __attribute__((ext_vector_type(4))) _Float16 h4;
typedef __attribute__((ext_vector_type(8))) _Float16 f16x8;
typedef __attribute__((ext_vector_type(4))) float f32x4;

static inline size_t align_up(size_t x, size_t a) { return (x + a - 1) & ~(a - 1); }

__device__ __forceinline__ f4 h2f(h4 v) { return __builtin_convertvector(v, f4); }
__device__ __forceinline__ h4 f2h(f4 v) { return __builtin_convertvector(v, h4); }
__device__ __forceinline__ f32x8 h2f8(f16x8 v) { return __builtin_convertvector(v, f32x8); }

__global__ __launch_bounds__(256) void k_cvt(const float* __restrict__ in,
                                             _Float16* __restrict__ out) {
    int i = blockIdx.x * blockDim.x + threadIdx.x;
    f4 v = *(const f4*)(in + (size_t)i * 4);
    *(h4*)(out + (size_t)i * 4) = f2h(v);
}

// Build wT fp16 [L][2][j][k] from W_rel/W_root fp32 [L][k][j]
__global__ __launch_bounds__(128) void k_wprep(
    const float* __restrict__ W_rel, const float* __restrict__ W_root,
    _Float16* __restrict__ wT) {
    const int b = blockIdx.x;
    const int l = b >> 8;
    const int m = (b >> 7) & 1;
    const int j = b & 127;
    const int k = threadIdx.x;
    const float* W = (m == 0 ? W_rel : W_root) + (size_t)l * HID * HID;
    wT[(((size_t)l * 2 + m) * HID + j) * HID + k] = (_Float16)W[k * HID + j];
}

// ==================== CSR build: 2-pass LDS-staged bucket sort ====================

__global__ __launch_bounds__(256) void k_zeroB(int* __restrict__ b) { b[threadIdx.x] = 0; }

__global__ __launch_bounds__(256) void k_hist1(const int* __restrict__ dst,
                                               int* __restrict__ bhist) {
    __shared__ int h[NBUCK];
    h[threadIdx.x] = 0;
    __syncthreads();
    int stride = gridDim.x * blockDim.x;
    for (int e = blockIdx.x * 256 + threadIdx.x; e < N_EDGES_C; e += stride)
        atomicAdd(&h[dst[e] / BSZ], 1);
    __syncthreads();
    if (h[threadIdx.x]) atomicAdd(&bhist[threadIdx.x], h[threadIdx.x]);
}

__global__ __launch_bounds__(256) void k_bscan(const int* __restrict__ bhist,
                                               int* __restrict__ bbase,
                                               int* __restrict__ bcursor) {
    __shared__ int s[NBUCK];
    const int tid = threadIdx.x;
    int v = bhist[tid];
    s[tid] = v;
    __syncthreads();
    for (int off = 1; off < NBUCK; off <<= 1) {
        int t = (tid >= off) ? s[tid - off] : 0;
        __syncthreads();
        s[tid] += t;
        __syncthreads();
    }
    int excl = s[tid] - v;
    bbase[tid] = excl;
    bcursor[tid] = excl;
    if (tid == NBUCK - 1) bbase[NBUCK] = N_EDGES_C;
}

__global__ __launch_bounds__(256) void k_scatter1(
    const int* __restrict__ src, const int* __restrict__ dst,
    int* __restrict__ bcursor, unsigned* __restrict__ tmp) {
    __shared__ int h[NBUCK], sc[NBUCK], gb[NBUCK], lc[NBUCK];
    __shared__ unsigned lbuf[CHUNK];
    const int tid = threadIdx.x;
    const int base = blockIdx.x * CHUNK;
    h[tid] = 0; lc[tid] = 0;
    __syncthreads();
    unsigned rec[EPT]; int bk[EPT];
#pragma unroll
    for (int i = 0; i < EPT; ++i) {
        int e = base + i * 256 + tid;
        if (e < N_EDGES_C) {
            int d = dst[e];
            int b = d / BSZ;
            rec[i] = ((unsigned)src[e] << 9) | (unsigned)(d - b * BSZ);
            bk[i] = b;
            atomicAdd(&h[b], 1);
        } else bk[i] = -1;
    }
    __syncthreads();
    int v = h[tid];
    sc[tid] = v;
    __syncthreads();
    for (int off = 1; off < NBUCK; off <<= 1) {
        int t = (tid >= off) ? sc[tid - off] : 0;
        __syncthreads();
        sc[tid] += t;
        __syncthreads();
    }
    int excl = sc[tid] - v;
    gb[tid] = v ? atomicAdd(&bcursor[tid], v) : 0;
    sc[tid] = excl;
    __syncthreads();
#pragma unroll
    for (int i = 0; i < EPT; ++i) {
        if (bk[i] >= 0) {
            int p = atomicAdd(&lc[bk[i]], 1);
            lbuf[sc[bk[i]] + p] = rec[i];
        }
    }
    __syncthreads();
    const int wid = tid >> 6, lane = tid & 63;
    for (int b = wid; b < NBUCK; b += 4) {
        int n = h[b], g = gb[b], l = sc[b];
        for (int i = lane; i < n; i += 64) tmp[g + i] = lbuf[l + i];
    }
}

__global__ __launch_bounds__(256) void k_sort2(
    const unsigned* __restrict__ tmp, const int* __restrict__ bbase,
    int* __restrict__ offsets, int* __restrict__ es) {
    __shared__ int h[512], s2[512], cur[512];
    __shared__ int lbuf[BCAP];
    const int b = blockIdx.x, tid = threadIdx.x;
    const int base = bbase[b];
    const int cnt = bbase[b + 1] - base;
    h[tid] = 0; h[tid + 256] = 0;
    __syncthreads();
    for (int i = tid; i < cnt; i += 256) atomicAdd(&h[tmp[base + i] & 511], 1);
    __syncthreads();
    int v0 = h[tid], v1 = h[tid + 256];
    s2[tid] = v0; s2[tid + 256] = v1;
    __syncthreads();
    for (int off = 1; off < 512; off <<= 1) {
        int t0 = (tid >= off) ? s2[tid - off] : 0;
        int t1 = (tid + 256 >= off) ? s2[tid + 256 - off] : 0;
        __syncthreads();
        s2[tid] += t0; s2[tid + 256] += t1;
        __syncthreads();
    }
    int e0 = s2[tid] - v0, e1 = s2[tid + 256] - v1;
    cur[tid] = e0; cur[tid + 256] = e1;
    {
        int gn0 = b * BSZ + tid;
        if (tid < BSZ && gn0 < N_NODES_C) offsets[gn0] = base + e0;
        int n1 = tid + 256;
        int gn1 = b * BSZ + n1;
        if (n1 < BSZ && gn1 < N_NODES_C) offsets[gn1] = base + e1;
    }
    __syncthreads();
    for (int i = tid; i < cnt; i += 256) {
        unsigned r = tmp[base + i];
        int ld = r & 511;
        int p = atomicAdd(&cur[ld], 1);
        lbuf[p] = (int)(r >> 9);
    }
    __syncthreads();
    for (int i = tid; i < cnt; i += 256) es[base + i] = lbuf[i];
    if (b == NBUCK - 1 && tid == 0) offsets[N_NODES_C] = N_EDGES_C;
}

// ==================== layers ====================

// Gather-sum: 16-lane group per node (f16x8 = 16B/lane -> one wave-load covers
// 4 rows = 1KB, half the VMEM instructions of the 32-lane/8B version).
// fp32 accumulate in 4x f32x8, loads 8-deep ILP. No LDS, no barriers.
__global__ __launch_bounds__(256) void k_gather(
    const _Float16* __restrict__ h_in, _Float16* __restrict__ agg,
    const int* __restrict__ offsets, const int* __restrict__ es) {
    const int node = (blockIdx.x << 4) + (threadIdx.x >> 4);  // 16 groups/block
    const int lane = threadIdx.x & 15;
    const int c8 = lane * 8;
    const int beg = offsets[node];
    const int end = offsets[node + 1];
    f32x8 a0 = {0.f, 0.f, 0.f, 0.f, 0.f, 0.f, 0.f, 0.f};
    f32x8 a1 = a0, a2 = a0, a3 = a0;
    int e = beg;
    for (; e + 8 <= end; e += 8) {
        int s0 = es[e],     s1 = es[e + 1], s2 = es[e + 2], s3 = es[e + 3];
        int s4 = es[e + 4], s5 = es[e + 5], s6 = es[e + 6], s7 = es[e + 7];
        f16x8 v0 = *(const f16x8*)(h_in + (size_t)s0 * HID + c8);
        f16x8 v1 = *(const f16x8*)(h_in + (size_t)s1 * HID + c8);
        f16x8 v2 = *(const f16x8*)(h_in + (size_t)s2 * HID + c8);
        f16x8 v3 = *(const f16x8*)(h_in + (size_t)s3 * HID + c8);
        f16x8 v4 = *(const f16x8*)(h_in + (size_t)s4 * HID + c8);
        f16x8 v5 = *(const f16x8*)(h_in + (size_t)s5 * HID + c8);
        f16x8 v6 = *(const f16x8*)(h_in + (size_t)s6 * HID + c8);
        f16x8 v7 = *(const f16x8*)(h_in + (size_t)s7 * HID + c8);
        a0 += h2f8(v0); a1 += h2f8(v1); a2 += h2f8(v2); a3 += h2f8(v3);
        a0 += h2f8(v4); a1 += h2f8(v5); a2 += h2f8(v6); a3 += h2f8(v7);
    }
    for (; e + 4 <= end; e += 4) {
        int s0 = es[e], s1 = es[e + 1], s2 = es[e + 2], s3 = es[e + 3];
        f16x8 v0 = *(const f16x8*)(h_in + (size_t)s0 * HID + c8);
        f16x8 v1 = *(const f16x8*)(h_in + (size_t)s1 * HID + c8);
        f16x8 v2 = *(const f16x8*)(h_in + (size_t)s2 * HID + c8);
        f16x8 v3 = *(const f16x8*)(h_in + (size_t)s3 * HID + c8);
        a0 += h2f8(v0); a1 += h2f8(v1); a2 += h2f8(v2); a3 += h2f8(v3);
    }
    for (; e < end; ++e)
        a0 += h2f8(*(const f16x8*)(h_in + (size_t)es[e] * HID + c8));
    f32x8 t = (a0 + a1) + (a2 + a3);
    *(f16x8*)(agg + (size_t)node * HID + c8) = __builtin_convertvector(t, f16x8);
}

// MFMA GEMM, LDS-staged (confirmed fix for the L2-transaction bound, r21).
__global__ __launch_bounds__(256) void k_gemm_mfma(
    const _Float16* __restrict__ agg, const _Float16* __restrict__ h_in,
    _Float16* __restrict__ h_out,
    const _Float16* __restrict__ wT,   // [2][HID][HID] (j,k) for this layer
    const float* __restrict__ b_rel) {
    __shared__ _Float16 ldsA[GT * HID];  // 16 KB, seg-swizzled
    __shared__ _Float16 ldsH[GT * HID];  // 16 KB
    const int tid = threadIdx.x;
    const int lane = tid & 63;
    const int wv = tid >> 6;        // 0..3
    const int row16 = lane & 15;
    const int kg = lane >> 4;       // 0..3

    f16x8 WR[2][4], WO[2][4];
    float bb[2];
#pragma unroll
    for (int p = 0; p < 2; ++p) {
        const int j = ((2 * wv + p) << 4) + row16;
        const _Float16* wr = wT + (size_t)j * HID + (kg << 3);
        const _Float16* wo = wT + (size_t)(HID + j) * HID + (kg << 3);
#pragma unroll
        for (int s = 0; s < 4; ++s) {
            WR[p][s] = *(const f16x8*)(wr + s * 32);
            WO[p][s] = *(const f16x8*)(wo + s * 32);
        }
        bb[p] = b_rel[j];
    }

    for (int t = blockIdx.x; t < GTILES; t += GBLOCKS) {
        const int n0 = t * GT;
        __syncthreads();  // protect previous iteration's LDS reads
#pragma unroll
        for (int rnd = 0; rnd < 4; ++rnd) {
            const int idx = rnd * 256 + tid;  // 0..1023
            const int r = idx >> 4;           // row 0..63
            const int s = idx & 15;           // seg 0..15
            int n = n0 + r;
            if (n >= N_NODES_C) n = N_NODES_C - 1;  // clamp (stores guarded)
            const int sp = s ^ (r & 7);             // XOR swizzle
            *(f16x8*)(ldsA + ((size_t)r * 16 + sp) * 8) =
                *(const f16x8*)(agg + (size_t)n * HID + s * 8);
            *(f16x8*)(ldsH + ((size_t)r * 16 + sp) * 8) =
                *(const f16x8*)(h_in + (size_t)n * HID + s * 8);
        }
        __syncthreads();
#pragma unroll
        for (int p = 0; p < 2; ++p) {
            const int j = ((2 * wv + p) << 4) + row16;
#pragma unroll
            for (int nt = 0; nt < 4; ++nt) {
                const int r = nt * 16 + row16;  // A-row in tile
                f16x8 fA[4], fH[4];
#pragma unroll
                for (int s = 0; s < 4; ++s) {
                    const int sp = (s * 4 + kg) ^ (r & 7);
                    fA[s] = *(const f16x8*)(ldsA + ((size_t)r * 16 + sp) * 8);
                    fH[s] = *(const f16x8*)(ldsH + ((size_t)r * 16 + sp) * 8);
                }
                f32x4 a1 = {0.f, 0.f, 0.f, 0.f}, a2 = a1;
                a1 = __builtin_amdgcn_mfma_f32_16x16x32_f16(fA[0], WR[p][0], a1, 0, 0, 0);
                a2 = __builtin_amdgcn_mfma_f32_16x16x32_f16(fA[2], WR[p][2], a2, 0, 0, 0);
                a1 = __builtin_amdgcn_mfma_f32_16x16x32_f16(fH[0], WO[p][0], a1, 0, 0, 0);
                a2 = __builtin_amdgcn_mfma_f32_16x16x32_f16(fH[2], WO[p][2], a2, 0, 0, 0);
                a1 = __builtin_amdgcn_mfma_f32_16x16x32_f16(fA[1], WR[p][1], a1, 0, 0, 0);
                a2 = __builtin_amdgcn_mfma_f32_16x16x32_f16(fA[3], WR[p][3], a2, 0, 0, 0);
                a1 = __builtin_amdgcn_mfma_f32_16x16x32_f16(fH[1], WO[p][1], a1, 0, 0, 0);
                a2 = __builtin_amdgcn_mfma_f32_16x16x32_f16(fH[3], WO[p][3], a2, 0, 0, 0);
                const f32x4 acc = a1 + a2;
#pragma unroll
                for (int rr = 0; rr < 4; ++rr) {
                    const int n = n0 + nt * 16 + (kg << 2) + rr;
                    if (n < N_NODES_C)
                        h_out[(size_t)n * HID + j] = (_Float16)atanf(acc[rr] + bb[p]);
                }
            }
        }
    }
}

// Pool stage 1: per (graph, segment) partial sums over fp16 h -> fp32 part
__global__ __launch_bounds__(256) void k_pool1(
    const _Float16* __restrict__ h, const int* __restrict__ batch,
    float* __restrict__ part) {
    __shared__ float sm[2][HID];
    const int b = blockIdx.x;
    const int g = b >> 3, s = b & (SEG - 1);
    const int j = threadIdx.x & 127;
    const int half = threadIdx.x >> 7;

    int lo = 0, hi = N_NODES_C;
    while (lo < hi) { int mid = (lo + hi) >> 1; if (batch[mid] < g) lo = mid + 1; else hi = mid; }
    int start = lo;
    hi = N_NODES_C;
    while (lo < hi) { int mid = (lo + hi) >> 1; if (batch[mid] < g + 1) lo = mid + 1; else hi = mid; }
    int end = lo;
    int len = end - start;
    int s0 = start + (int)((long long)len * s / SEG);
    int s1 = start + (int)((long long)len * (s + 1) / SEG);

    float acc = 0.f;
    for (int i = s0 + half; i < s1; i += 2) acc += (float)h[(size_t)i * HID + j];
    sm[half][j] = acc;
    __syncthreads();
    if (threadIdx.x < HID) part[(size_t)b * HID + j] = sm[0][j] + sm[1][j];
}

// Pool stage 2 + head
__global__ __launch_bounds__(128) void k_head(
    const float* __restrict__ part, const float* __restrict__ W_out,
    const float* __restrict__ b_out, float* __restrict__ out) {
    __shared__ float sf[HID];
    const int g = blockIdx.x;
    const int j = threadIdx.x;
    float v = 0.f;
    for (int s = 0; s < SEG; ++s) v += part[(size_t)(g * SEG + s) * HID + j];
    sf[j] = v;
    __syncthreads();
    if (j < OUTD) {
        float a = b_out[j];
        for (int k = 0; k < HID; ++k) a += sf[k] * W_out[k * OUTD + j];
        out[g * OUTD + j] = 1.f / (1.f + expf(-a));
    }
}

extern "C" void kernel_launch(void* const* d_in, const int* in_sizes, int n_in,
                              void* d_out, int out_size, void* d_ws, size_t ws_size,
                              hipStream_t stream) {
    const float* x      = (const float*)d_in[0];
    const int*   ei     = (const int*)d_in[1];
    const int*   src    = ei;
    const int*   dst    = ei + N_EDGES_C;
    const int*   batch  = (const int*)d_in[2];
    const float* W_rel  = (const float*)d_in[3];
    const float* b_rel  = (const float*)d_in[4];
    const float* W_root = (const float*)d_in[5];
    const float* W_out  = (const float*)d_in[6];
    const float* b_out  = (const float*)d_in[7];
    float* out = (float*)d_out;

    char* ws = (char*)d_ws;
    size_t off = 0;
    auto alloc = [&](size_t bytes) { void* p = ws + off; off = align_up(off + bytes, 256); return p; };
    _Float16* xh    = (_Float16*)alloc((size_t)N_NODES_C * HID * 2);
    _Float16* h1h   = (_Float16*)alloc((size_t)N_NODES_C * HID * 2);
    _Float16* agg16 = (_Float16*)alloc((size_t)N_NODES_C * HID * 2);
    _Float16* wT    = (_Float16*)alloc((size_t)3 * 2 * HID * HID * 2);
    int*   offsets = (int*)alloc((size_t)(N_NODES_C + 1) * sizeof(int));
    int*   es      = (int*)alloc((size_t)N_EDGES_C * sizeof(int));
    unsigned* tmp  = (unsigned*)alloc((size_t)N_EDGES_C * sizeof(unsigned));
    int*   bhist   = (int*)alloc(NBUCK * sizeof(int));
    int*   bbase   = (int*)alloc((NBUCK + 1) * sizeof(int));
    int*   bcursor = (int*)alloc(NBUCK * sizeof(int));
    float* part    = (float*)alloc((size_t)N_GRAPHS_C * SEG * HID * sizeof(float));

    const int gather_blocks = N_NODES_C / 16;         // 6250
    const int scat_blocks = (N_EDGES_C + CHUNK - 1) / CHUNK;  // 391
    const size_t WTL = (size_t)2 * HID * HID;

    // ---- weight prep + x -> fp16 ----
    k_wprep<<<768, 128, 0, stream>>>(W_rel, W_root, wT);
    k_cvt<<<(N_NODES_C * HID) / 4 / 256, 256, 0, stream>>>(x, xh);

    // ---- CSR build: bucket sort, all global scatter staged through LDS ----
    k_zeroB<<<1, 256, 0, stream>>>(bhist);
    k_hist1<<<1024, 256, 0, stream>>>(dst, bhist);
    k_bscan<<<1, 256, 0, stream>>>(bhist, bbase, bcursor);
    k_scatter1<<<scat_blocks, 256, 0, stream>>>(src, dst, bcursor, tmp);
    k_sort2<<<NBUCK, 256, 0, stream>>>(tmp, bbase, offsets, es);

    // ---- 3 GraphConv layers: gather (wide-lane) + MFMA gemm (LDS-staged) ----
    k_gather<<<gather_blocks, 256, 0, stream>>>(xh, agg16, offsets, es);
    k_gemm_mfma<<<GBLOCKS, 256, 0, stream>>>(agg16, xh, h1h, wT + 0 * WTL, b_rel + 0 * HID);
    k_gather<<<gather_blocks, 256, 0, stream>>>(h1h, agg16, offsets, es);
    k_gemm_mfma<<<GBLOCKS, 256, 0, stream>>>(agg16, h1h, xh, wT + 1 * WTL, b_rel + 1 * HID);
    k_gather<<<gather_blocks, 256, 0, stream>>>(xh, agg16, offsets, es);
    k_gemm_mfma<<<GBLOCKS, 256, 0, stream>>>(agg16, xh, h1h, wT + 2 * WTL, b_rel + 2 * HID);

    // ---- pool + head ----
    k_pool1<<<N_GRAPHS_C * SEG, 256, 0, stream>>>(h1h, batch, part);
    k_head<<<N_GRAPHS_C, 128, 0, stream>>>(part, W_out, b_out, out);
}